// Round 14
// baseline (165.875 us; speedup 1.0000x reference)
//
#include <hip/hip_runtime.h>

#define EMB_DIM 256
#define HW 4096
#define N_EMB 1024
#define TOT_ELEMS (32 * HW * EMB_DIM)   // 33554432

typedef __attribute__((ext_vector_type(4)))  float f32x4;
typedef __attribute__((ext_vector_type(16))) float f32x16;
typedef __attribute__((ext_vector_type(4)))  int   i32x4;
typedef __attribute__((ext_vector_type(8)))  int   i32x8;

// ws layout (bytes)
#define WS_EMBQ_OFF 0             // 256 KB fp8(e4m3) swizzled emb, 16 chunks x 16KB
#define WS_E2_OFF   262144        // 1024 f32 ||e||^2 (fp32-exact)
#define WS_PSC_OFF  266240        // 256 f32 block partials

#define GRID_MAIN 256             // 1 block/CU; 8 waves = 4 producer + 4 consumer
#define ESCALE 65536.0f           // emb pre-scale: |e|<2^-10 -> |ê|<64 (normal e4m3)
#define INV2SCALE 3.0517578125e-5f // 2/65536, exact fp32
#define SCL_ONE 127               // e8m0: 2^0 neutral MX scale

typedef const __attribute__((address_space(1))) unsigned int* gas_u32p;
typedef __attribute__((address_space(3))) unsigned int* las_u32p;
__device__ __forceinline__ void gll16(const void* g, void* l) {
    __builtin_amdgcn_global_load_lds((gas_u32p)g, (las_u32p)l, 16, 0, 0);
}

// ---------------------------------------------------------------------------
// Kernel 0: emb fp32 -> fp8 e4m3 (x65536), swizzled chunk layout + e2=||e||^2.
// (verified R13: correct MX numerics, 0 LDS bank conflicts on the reader)
// ---------------------------------------------------------------------------
__global__ __launch_bounds__(64) void prep_emb(const float* __restrict__ emb,
                                               char* __restrict__ embq,
                                               float* __restrict__ e2) {
    const int e = blockIdx.x, ln = threadIdx.x;
    const float4 v = reinterpret_cast<const float4*>(emb)[e * 64 + ln];
    float s = v.x * v.x + v.y * v.y + v.z * v.z + v.w * v.w;

    unsigned d = 0;
    d = (unsigned)__builtin_amdgcn_cvt_pk_fp8_f32(v.x * ESCALE, v.y * ESCALE, (int)d, false);
    d = (unsigned)__builtin_amdgcn_cvt_pk_fp8_f32(v.z * ESCALE, v.w * ESCALE, (int)d, true);

    const int el = e & 63, ch = e >> 6;
    const int cb = (ln * 4) ^ ((el & 15) << 4);
    *reinterpret_cast<unsigned*>(embq + ch * 16384 + el * 256 + cb) = d;

#pragma unroll
    for (int o = 32; o; o >>= 1) s += __shfl_down(s, o);
    if (ln == 0) e2[e] = s;
}

// ---------------------------------------------------------------------------
// Kernel 1: producer/consumer fused copy + sum(x^2) + MX-fp8 GEMM + min.
// 8 waves: wv 0-3 PRODUCERS (all HBM IO: x float4 load -> out store + x^2 +
// ds_write slab; emb gll16 staging), wv 4-7 CONSUMERS (fragment build from
// slab + R13's verified MX e-loop; zero global traffic except L1-hot e2).
// 4 slices x 128 rows per block; slice s+1's x-windows staged at chunk
// phases 0/4/8/12 of slice s, consumer-built at c+1 into the alternate AGPR
// set. ONE uniform __syncthreads per phase (no divergent barriers).
// Slab [k][132f] pad: producer b128 row-writes, consumer column reads 2-way.
// MFMA mfma_scale_f32_32x32x64_f8f6f4, neutral scales (R13-verified layout).
// score = e2 - 2^-15 * (A.B)
// ---------------------------------------------------------------------------
__global__ __launch_bounds__(512)
void vq_main(const float* __restrict__ x,
             float* __restrict__ out,
             const char* __restrict__ embq,
             const float* __restrict__ e2,
             float* __restrict__ psc) {
    __shared__ char  emblds[32768];        // 2 x 16KB emb chunk buffers
    __shared__ float slab[64 * 132];       // x window: 64 k-rows x 128 n (+4 pad)
    __shared__ float redbuf[8];
    const int tid = threadIdx.x;
    const int wv = tid >> 6, ln = tid & 63;
    const bool prod = (wv < 4);
    const int cw = wv & 3;                 // consumer wave id / producer sub-id
    const int m = ln & 31, h = ln >> 5;    // consumer: x-row lane, k-half
    const int tid2 = cw * 64 + ln;         // producer flat id 0..255

    const int row_blk = blockIdx.x << 9;   // 512 rows/block (4 slices x 128)
    const int b = row_blk >> 12, n_base = row_blk & 4095;
    const unsigned xbase = (unsigned)(b * (EMB_DIM * HW) + n_base);

    float x2s = 0.f;                       // producers
    float best = 3.0e38f, sumb = 0.f;      // consumers
    i32x8 bxA[4], bxB[4];
    const int sw = (m & 15) << 4;

#define STAGE_EMB(CC, BUF) do {                                               \
        const char* gs_ = embq + (CC) * 16384 + cw * 4096 + ln * 16;          \
        char* lb_ = emblds + (BUF) * 16384 + cw * 4096;                       \
        _Pragma("unroll")                                                     \
        for (int i_ = 0; i_ < 4; ++i_) gll16(gs_ + i_ * 1024, lb_ + i_ * 1024); \
    } while (0)

    // producer: stage x window W (k in [64W,64W+64)) of slice SL: coalesced
    // float4 load -> out store + x^2 + slab row-write (b128, aligned).
#define STAGE_WIN(W, SL) do {                                                 \
        _Pragma("unroll")                                                     \
        for (int i_ = 0; i_ < 8; ++i_) {                                      \
            const int cell_ = i_ * 256 + tid2;                                \
            const int k_ = cell_ >> 5, nq_ = cell_ & 31;                      \
            const unsigned go_ = xbase +                                      \
                (unsigned)(((W) * 64 + k_) * HW + (SL) * 128 + 4 * nq_);      \
            const f32x4 v_ = *reinterpret_cast<const f32x4*>(x + go_);        \
            *reinterpret_cast<f32x4*>(out + go_) = v_;                        \
            x2s += v_[0]*v_[0] + v_[1]*v_[1] + v_[2]*v_[2] + v_[3]*v_[3];     \
            *reinterpret_cast<f32x4*>(&slab[k_ * 132 + 4 * nq_]) = v_;        \
        }                                                                     \
    } while (0)

    // consumer: build one MX B-fragment (32 k-bytes) for row cw*32+m from slab
#define BUILD(DST) do {                                                       \
        const float* sc_ = slab + (h * 32) * 132 + (cw * 32 + m);             \
        unsigned dw_[8];                                                      \
        _Pragma("unroll")                                                     \
        for (int d_ = 0; d_ < 8; ++d_) {                                      \
            const float f0_ = sc_[(4*d_+0)*132], f1_ = sc_[(4*d_+1)*132];     \
            const float f2_ = sc_[(4*d_+2)*132], f3_ = sc_[(4*d_+3)*132];     \
            unsigned t_ = 0;                                                  \
            t_ = (unsigned)__builtin_amdgcn_cvt_pk_fp8_f32(f0_, f1_, (int)t_, false); \
            t_ = (unsigned)__builtin_amdgcn_cvt_pk_fp8_f32(f2_, f3_, (int)t_, true);  \
            dw_[d_] = t_;                                                     \
        }                                                                     \
        i32x8 f8_;                                                            \
        _Pragma("unroll")                                                     \
        for (int d_ = 0; d_ < 8; ++d_) f8_[d_] = (int)dw_[d_];                \
        DST = f8_;                                                            \
        asm volatile("" : "+a"(DST));                                         \
    } while (0)

    // consumer: R13's verified MX e-chunk compute (chunk CC from emblds)
#define TLOOP(FR, CC) do {                                                    \
        const char* bufb_ = emblds + ((CC) & 1) * 16384;                      \
        const char* p0_ = bufb_ + m * 256;                                    \
        const char* p1_ = p0_ + 32 * 256;                                     \
        f32x16 a0_ = {0.f,0.f,0.f,0.f,0.f,0.f,0.f,0.f,0.f,0.f,0.f,0.f,0.f,0.f,0.f,0.f}; \
        f32x16 a1_ = a0_;                                                     \
        _Pragma("unroll")                                                     \
        for (int kf_ = 0; kf_ < 4; ++kf_) {                                   \
            const int bo_ = kf_ * 64 + h * 32;                                \
            const i32x4 lo0_ = *reinterpret_cast<const i32x4*>(p0_ + ((bo_)      ^ sw)); \
            const i32x4 hi0_ = *reinterpret_cast<const i32x4*>(p0_ + ((bo_ + 16) ^ sw)); \
            const i32x4 lo1_ = *reinterpret_cast<const i32x4*>(p1_ + ((bo_)      ^ sw)); \
            const i32x4 hi1_ = *reinterpret_cast<const i32x4*>(p1_ + ((bo_ + 16) ^ sw)); \
            i32x8 e0_, e1_;                                                   \
            _Pragma("unroll")                                                 \
            for (int d_ = 0; d_ < 4; ++d_) {                                  \
                e0_[d_] = lo0_[d_]; e0_[d_ + 4] = hi0_[d_];                   \
                e1_[d_] = lo1_[d_]; e1_[d_ + 4] = hi1_[d_];                   \
            }                                                                 \
            a0_ = __builtin_amdgcn_mfma_scale_f32_32x32x64_f8f6f4(            \
                      e0_, FR[kf_], a0_, 0, 0, 0, SCL_ONE, 0, SCL_ONE);       \
            a1_ = __builtin_amdgcn_mfma_scale_f32_32x32x64_f8f6f4(            \
                      e1_, FR[kf_], a1_, 0, 0, 0, SCL_ONE, 0, SCL_ONE);       \
        }                                                                     \
        _Pragma("unroll")                                                     \
        for (int q_ = 0; q_ < 4; ++q_) {                                      \
            const f32x4 ev0_ = *reinterpret_cast<const f32x4*>(e2 + (CC)*64 + q_*8 + h*4); \
            const f32x4 ev1_ = *reinterpret_cast<const f32x4*>(e2 + (CC)*64 + 32 + q_*8 + h*4); \
            _Pragma("unroll")                                                 \
            for (int r_ = 0; r_ < 4; ++r_) {                                  \
                best = fminf(best, fmaf(-INV2SCALE, a0_[q_*4+r_], ev0_[r_])); \
                best = fminf(best, fmaf(-INV2SCALE, a1_[q_*4+r_], ev1_[r_])); \
            }                                                                 \
        }                                                                     \
    } while (0)

    // one slice: consumers e-loop on CUR; producers stage emb chunks + (if
    // S<3) slice S+1's x-windows; consumers build NXT at window+1 phases.
#define SLICE(CUR, NXT, S, DOB) do {                                          \
        for (int c = 0; c < 16; ++c) {                                        \
            if (prod) {                                                       \
                if (c < 15) STAGE_EMB(c + 1, (c + 1) & 1);                    \
                else if ((S) < 3) STAGE_EMB(0, 0);                            \
                if (((c & 3) == 0) && (S) < 3) STAGE_WIN(c >> 2, (S) + 1);    \
            } else {                                                          \
                TLOOP(CUR, c);                                                \
                if ((DOB) && ((c & 3) == 1)) {                                \
                    switch (c >> 2) {                                         \
                        case 0: BUILD(NXT[0]); break;                         \
                        case 1: BUILD(NXT[1]); break;                         \
                        case 2: BUILD(NXT[2]); break;                         \
                        default: BUILD(NXT[3]); break;                        \
                    }                                                         \
                }                                                             \
            }                                                                 \
            __syncthreads();                                                  \
        }                                                                     \
        if (!prod) {                                                          \
            const float bm_ = fminf(best, __shfl_xor(best, 32));              \
            if (h == 0) sumb += bm_;                                          \
            best = 3.0e38f;                                                   \
        }                                                                     \
    } while (0)

    // ---- bootstrap: stage + build slice 0's four windows (8 phases) ----
#pragma unroll
    for (int w = 0; w < 4; ++w) {
        if (prod) {
            if (w == 0) STAGE_EMB(0, 0);
            switch (w) {
                case 0: STAGE_WIN(0, 0); break;
                case 1: STAGE_WIN(1, 0); break;
                case 2: STAGE_WIN(2, 0); break;
                default: STAGE_WIN(3, 0); break;
            }
        }
        __syncthreads();
        if (!prod) {
            switch (w) {
                case 0: BUILD(bxA[0]); break;
                case 1: BUILD(bxA[1]); break;
                case 2: BUILD(bxA[2]); break;
                default: BUILD(bxA[3]); break;
            }
        }
        __syncthreads();
    }

    SLICE(bxA, bxB, 0, 1);
    SLICE(bxB, bxA, 1, 1);
    SLICE(bxA, bxB, 2, 1);
    SLICE(bxB, bxA, 3, 0);

    // ---- block reduction: producers carry x^2, consumers carry mins ----
    float contrib = prod ? x2s : ((h == 0) ? sumb : 0.f);
#pragma unroll
    for (int o = 32; o; o >>= 1) contrib += __shfl_down(contrib, o);
    if (ln == 0) redbuf[wv] = contrib;
    __syncthreads();
    if (tid == 0) {
        float s = 0.f;
#pragma unroll
        for (int i = 0; i < 8; ++i) s += redbuf[i];
        psc[blockIdx.x] = s;
    }
#undef STAGE_EMB
#undef STAGE_WIN
#undef BUILD
#undef TLOOP
#undef SLICE
}

// ---------------------------------------------------------------------------
// Kernel 2: deterministic tree-reduce of partials -> loss scalar.
// ---------------------------------------------------------------------------
__global__ __launch_bounds__(256) void finalize(const float* __restrict__ psc,
                                                float* __restrict__ out_loss) {
    __shared__ float red[256];
    const int t = threadIdx.x;
    red[t] = psc[t];
    __syncthreads();
    for (int hh = 128; hh; hh >>= 1) {
        if (t < hh) red[t] += red[t + hh];
        __syncthreads();
    }
    if (t == 0) *out_loss = 1.25f * red[0] / (float)TOT_ELEMS;
}

extern "C" void kernel_launch(void* const* d_in, const int* in_sizes, int n_in,
                              void* d_out, int out_size, void* d_ws, size_t ws_size,
                              hipStream_t stream) {
    const float* x = (const float*)d_in[0];
    const float* emb = (const float*)d_in[1];
    float* out = (float*)d_out;
    char* ws = (char*)d_ws;

    char*  embq = ws + WS_EMBQ_OFF;
    float* e2   = (float*)(ws + WS_E2_OFF);
    float* psc  = (float*)(ws + WS_PSC_OFF);

    prep_emb<<<N_EMB, 64, 0, stream>>>(emb, embq, e2);
    vq_main<<<GRID_MAIN, 512, 0, stream>>>(x, out, embq, e2, psc);
    finalize<<<1, 256, 0, stream>>>(psc, out + TOT_ELEMS);
}